// Round 10
// baseline (736.298 us; speedup 1.0000x reference)
//
#include <hip/hip_runtime.h>

#define D 128
#define LRELU(x) ((x) > 0.f ? (x) : 0.2f * (x))

// ---------------- edge-index width detection ----------------
__global__ void detect_i64(const unsigned int* ei, int* flag) {
    if (threadIdx.x == 0 && blockIdx.x == 0) {
        unsigned int o = 0;
#pragma unroll
        for (int k = 0; k < 64; ++k) o |= ei[2 * k + 1];
        *flag = (o == 0u) ? 1 : 0;
    }
}

__device__ __forceinline__ int load_idx(const void* ei, long long pos, int is64) {
    if (is64) return (int)((const long long*)ei)[pos];
    return ((const int*)ei)[pos];
}

// ---------------- CSR construction ----------------
__global__ void hist_kernel(const void* __restrict__ ei, const int* __restrict__ flag,
                            int* __restrict__ count, int E) {
    int e = blockIdx.x * blockDim.x + threadIdx.x;
    if (e >= E) return;
    int is64 = *flag;
    int dst = load_idx(ei, (long long)E + e, is64);
    atomicAdd(&count[dst], 1);
}

__global__ void reduce_1024(const int* __restrict__ count, int* __restrict__ bsum, int n) {
    __shared__ int sm[256];
    int t = threadIdx.x, b = blockIdx.x;
    int base = b * 1024 + t * 4;
    int s = 0;
#pragma unroll
    for (int j = 0; j < 4; ++j)
        if (base + j < n) s += count[base + j];
    sm[t] = s;
    __syncthreads();
    for (int of = 128; of >= 1; of >>= 1) {
        if (t < of) sm[t] += sm[t + of];
        __syncthreads();
    }
    if (t == 0) bsum[b] = sm[0];
}

__global__ void scan_partials(int* __restrict__ bsum_ex, const int* __restrict__ bsum, int B) {
    __shared__ int sm[256];
    int t = threadIdx.x;
    int v = (t < B) ? bsum[t] : 0;
    sm[t] = v;
    __syncthreads();
    for (int of = 1; of < 256; of <<= 1) {
        int u = (t >= of) ? sm[t - of] : 0;
        __syncthreads();
        sm[t] += u;
        __syncthreads();
    }
    if (t < B) bsum_ex[t] = sm[t] - v;
}

__global__ void scan_final(const int* __restrict__ count, const int* __restrict__ bsum_ex,
                           int* __restrict__ offsets, int n) {
    __shared__ int sm[256];
    int t = threadIdx.x, b = blockIdx.x;
    int base = b * 1024 + t * 4;
    int c[4];
#pragma unroll
    for (int j = 0; j < 4; ++j) c[j] = (base + j < n) ? count[base + j] : 0;
    int tsum = c[0] + c[1] + c[2] + c[3];
    sm[t] = tsum;
    __syncthreads();
    for (int of = 1; of < 256; of <<= 1) {
        int u = (t >= of) ? sm[t - of] : 0;
        __syncthreads();
        sm[t] += u;
        __syncthreads();
    }
    int o = bsum_ex[b] + sm[t] - tsum;
#pragma unroll
    for (int j = 0; j < 4; ++j) {
        if (base + j < n) offsets[base + j] = o;
        o += c[j];
    }
}

__global__ void scatter_kernel(const void* __restrict__ ei, const int* __restrict__ flag,
                               const int* __restrict__ offsets, int* __restrict__ cursor,
                               int* __restrict__ col, int E) {
    int e = blockIdx.x * blockDim.x + threadIdx.x;
    if (e >= E) return;
    int is64 = *flag;
    int src = load_idx(ei, e, is64);
    int dst = load_idx(ei, (long long)E + e, is64);
    int pos = offsets[dst] + atomicAdd(&cursor[dst], 1);
    col[pos] = src;
}

// ---------------- f32 GEMM: Y = X @ W, output in PAIRED layout ----------------
// Paired layout: for node r, pair p (0..63) holds (col p, col p+64) at floats
// [r*128 + 2p, r*128 + 2p + 1]. Gather in aggregate reads one dwordx2 per lane.
__launch_bounds__(256, 2)
__global__ void gemm_nn_128(const float* __restrict__ X, const float* __restrict__ W,
                            float* __restrict__ Yp, int n) {
    __shared__ float Xt[64][68];   // [k][r]
    __shared__ float Wl[64][128];  // [k][c]
    const int t = threadIdx.x;
    const int r0 = blockIdx.x * 64;
    const int rb = (t >> 4) * 4;
    const int cb = (t & 15) * 4;
    float acc[4][8] = {};
    for (int ph = 0; ph < 2; ++ph) {
#pragma unroll
        for (int it = 0; it < 4; ++it) {
            int idx = t + it * 256;
            int r = idx >> 4, kq = idx & 15;
            float4 xv = make_float4(0.f, 0.f, 0.f, 0.f);
            if (r0 + r < n)
                xv = *reinterpret_cast<const float4*>(X + (size_t)(r0 + r) * D + ph * 64 + kq * 4);
            Xt[kq * 4 + 0][r] = xv.x;
            Xt[kq * 4 + 1][r] = xv.y;
            Xt[kq * 4 + 2][r] = xv.z;
            Xt[kq * 4 + 3][r] = xv.w;
        }
#pragma unroll
        for (int it = 0; it < 8; ++it) {
            int idx = t + it * 256;
            int k = idx >> 5, c4 = idx & 31;
            *reinterpret_cast<float4*>(&Wl[k][c4 * 4]) =
                *reinterpret_cast<const float4*>(W + (size_t)(ph * 64 + k) * D + c4 * 4);
        }
        __syncthreads();
#pragma unroll 4
        for (int k = 0; k < 64; ++k) {
            float4 a = *reinterpret_cast<const float4*>(&Xt[k][rb]);
            float4 b0 = *reinterpret_cast<const float4*>(&Wl[k][cb]);
            float4 b1 = *reinterpret_cast<const float4*>(&Wl[k][cb + 64]);
            float av[4] = {a.x, a.y, a.z, a.w};
            float bv[8] = {b0.x, b0.y, b0.z, b0.w, b1.x, b1.y, b1.z, b1.w};
#pragma unroll
            for (int i = 0; i < 4; ++i)
#pragma unroll
                for (int j = 0; j < 8; ++j) acc[i][j] = fmaf(av[i], bv[j], acc[i][j]);
        }
        __syncthreads();
    }
#pragma unroll
    for (int i = 0; i < 4; ++i) {
        int row = r0 + rb + i;
        if (row < n) {
            float4 o0 = make_float4(acc[i][0], acc[i][4], acc[i][1], acc[i][5]);
            float4 o1 = make_float4(acc[i][2], acc[i][6], acc[i][3], acc[i][7]);
            *reinterpret_cast<float4*>(Yp + (size_t)row * D + 2 * cb) = o0;
            *reinterpret_cast<float4*>(Yp + (size_t)row * D + 2 * cb + 4) = o1;
        }
    }
}

// ---------------- attention scores from paired xp ----------------
template <int H>
__launch_bounds__(256)
__global__ void score_kernel(const float* __restrict__ xp2, const float* __restrict__ a_src,
                             const float* __restrict__ a_dst, float* __restrict__ s_src,
                             float* __restrict__ s_dst, int n) {
    int wid = (blockIdx.x * 256 + threadIdx.x) >> 6;
    int lane = threadIdx.x & 63;
    if (wid >= n) return;
    float2 xv = reinterpret_cast<const float2*>(xp2 + (size_t)wid * D)[lane];
    float x0 = xv.x, x1 = xv.y;  // channels lane, lane+64
    float ps0 = x0 * a_src[lane], ps1 = x1 * a_src[lane + 64];
    float pd0 = x0 * a_dst[lane], pd1 = x1 * a_dst[lane + 64];
    if (H == 4) {
        for (int m = 16; m >= 1; m >>= 1) {
            ps0 += __shfl_xor(ps0, m);
            ps1 += __shfl_xor(ps1, m);
            pd0 += __shfl_xor(pd0, m);
            pd1 += __shfl_xor(pd1, m);
        }
        if (lane == 0) {
            s_src[wid * 4 + 0] = ps0; s_src[wid * 4 + 2] = ps1;
            s_dst[wid * 4 + 0] = pd0; s_dst[wid * 4 + 2] = pd1;
        }
        if (lane == 32) {
            s_src[wid * 4 + 1] = ps0; s_src[wid * 4 + 3] = ps1;
            s_dst[wid * 4 + 1] = pd0; s_dst[wid * 4 + 3] = pd1;
        }
    } else {
        float ps = ps0 + ps1, pd = pd0 + pd1;
        for (int m = 32; m >= 1; m >>= 1) {
            ps += __shfl_xor(ps, m);
            pd += __shfl_xor(pd, m);
        }
        if (lane == 0) { s_src[wid] = ps; s_dst[wid] = pd; }
    }
}

// ---------------- per-node softmax stats + per-edge weights ----------------
// Wave per node; lanes own EDGES (scalar work distributed, not replicated).
// Pass 1: gather s_src[col], compute e = lrelu(ss+sd), store (permuted), max.
// Pass 2: sequential re-read, w = exp(e-m), store back, sum.
// Writes per-node selfw and rd (permuted (h0,h2,h1,h3) so aggregate reads float2).
template <int H>
__launch_bounds__(256)
__global__ void stats_weights(const int* __restrict__ col, const int* __restrict__ offsets,
                              const int* __restrict__ deg_arr, const float* __restrict__ s_src,
                              const float* __restrict__ s_dst, float* __restrict__ wbuf,
                              float* __restrict__ swbuf, float* __restrict__ rdbuf, int n) {
    int wid = (blockIdx.x * 256 + threadIdx.x) >> 6;
    int lane = threadIdx.x & 63;
    if (wid >= n) return;
    int off = __builtin_amdgcn_readfirstlane(offsets[wid]);
    int deg = __builtin_amdgcn_readfirstlane(deg_arr[wid]);
    if (H == 4) {
        float4 sdv = *reinterpret_cast<const float4*>(s_dst + (size_t)wid * 4);
        float4 ssv = *reinterpret_cast<const float4*>(s_src + (size_t)wid * 4);
        float es0 = LRELU(ssv.x + sdv.x), es1 = LRELU(ssv.y + sdv.y);
        float es2 = LRELU(ssv.z + sdv.z), es3 = LRELU(ssv.w + sdv.w);
        float m0 = es0, m1 = es1, m2 = es2, m3 = es3;
        for (int i = lane; i < deg; i += 64) {
            int c = col[off + i];
            float4 q = *reinterpret_cast<const float4*>(s_src + (size_t)c * 4);
            float e0 = LRELU(q.x + sdv.x), e1 = LRELU(q.y + sdv.y);
            float e2 = LRELU(q.z + sdv.z), e3 = LRELU(q.w + sdv.w);
            m0 = fmaxf(m0, e0); m1 = fmaxf(m1, e1);
            m2 = fmaxf(m2, e2); m3 = fmaxf(m3, e3);
            // permuted store: (h0, h2, h1, h3) to match aggregate's half-wave float2 read
            *reinterpret_cast<float4*>(wbuf + (size_t)(off + i) * 4) = make_float4(e0, e2, e1, e3);
        }
        for (int s = 32; s >= 1; s >>= 1) {
            m0 = fmaxf(m0, __shfl_xor(m0, s)); m1 = fmaxf(m1, __shfl_xor(m1, s));
            m2 = fmaxf(m2, __shfl_xor(m2, s)); m3 = fmaxf(m3, __shfl_xor(m3, s));
        }
        float s0 = 0.f, s1 = 0.f, s2 = 0.f, s3 = 0.f;
        for (int i = lane; i < deg; i += 64) {
            float4 f = *reinterpret_cast<const float4*>(wbuf + (size_t)(off + i) * 4);
            float w0 = __expf(f.x - m0), w2 = __expf(f.y - m2);
            float w1 = __expf(f.z - m1), w3 = __expf(f.w - m3);
            *reinterpret_cast<float4*>(wbuf + (size_t)(off + i) * 4) = make_float4(w0, w2, w1, w3);
            s0 += w0; s1 += w1; s2 += w2; s3 += w3;
        }
        for (int s = 32; s >= 1; s >>= 1) {
            s0 += __shfl_xor(s0, s); s1 += __shfl_xor(s1, s);
            s2 += __shfl_xor(s2, s); s3 += __shfl_xor(s3, s);
        }
        if (lane == 0) {
            float sw0 = __expf(es0 - m0), sw1 = __expf(es1 - m1);
            float sw2 = __expf(es2 - m2), sw3 = __expf(es3 - m3);
            float r0 = 1.f / (s0 + sw0 + 1e-16f), r1 = 1.f / (s1 + sw1 + 1e-16f);
            float r2 = 1.f / (s2 + sw2 + 1e-16f), r3 = 1.f / (s3 + sw3 + 1e-16f);
            *reinterpret_cast<float4*>(swbuf + (size_t)wid * 4) = make_float4(sw0, sw2, sw1, sw3);
            *reinterpret_cast<float4*>(rdbuf + (size_t)wid * 4) = make_float4(r0, r2, r1, r3);
        }
    } else {
        float sd = s_dst[wid];
        float es = LRELU(s_src[wid] + sd);
        float m = es;
        for (int i = lane; i < deg; i += 64) {
            int c = col[off + i];
            float e = LRELU(s_src[c] + sd);
            m = fmaxf(m, e);
            wbuf[off + i] = e;
        }
        for (int s = 32; s >= 1; s >>= 1) m = fmaxf(m, __shfl_xor(m, s));
        float sum = 0.f;
        for (int i = lane; i < deg; i += 64) {
            float w = __expf(wbuf[off + i] - m);
            wbuf[off + i] = w;
            sum += w;
        }
        for (int s = 32; s >= 1; s >>= 1) sum += __shfl_xor(sum, s);
        if (lane == 0) {
            float sw = __expf(es - m);
            swbuf[wid] = sw;
            rdbuf[wid] = 1.f / (sum + sw + 1e-16f);
        }
    }
}

// ---------------- weighted aggregation with precomputed weights ----------------
// Wave per node; lanes own channels. Per edge: readlane col -> SGPR base,
// one broadcast float2 of w, one float2 xp gather, 2 fma. Minimal VALU.
template <int H, bool DO_ELU>
__launch_bounds__(256)
__global__ void aggregate_w(const int* __restrict__ col, const int* __restrict__ offsets,
                            const int* __restrict__ deg_arr, const float* __restrict__ xp2,
                            const float* __restrict__ wbuf, const float* __restrict__ swbuf,
                            const float* __restrict__ rdbuf, const float* __restrict__ bias,
                            float* __restrict__ out, int n) {
    int wid = (blockIdx.x * 256 + threadIdx.x) >> 6;
    int lane = threadIdx.x & 63;
    if (wid >= n) return;
    int off = __builtin_amdgcn_readfirstlane(offsets[wid]);
    int deg = __builtin_amdgcn_readfirstlane(deg_arr[wid]);
    const int half = lane >> 5;
    float swA, swB, rdA, rdB;
    if (H == 4) {
        float2 sw = reinterpret_cast<const float2*>(swbuf)[(size_t)wid * 2 + half];
        float2 rd = reinterpret_cast<const float2*>(rdbuf)[(size_t)wid * 2 + half];
        swA = sw.x; swB = sw.y; rdA = rd.x; rdB = rd.y;
    } else {
        swA = swB = swbuf[wid];
        rdA = rdB = rdbuf[wid];
    }
    float2 xs = reinterpret_cast<const float2*>(xp2 + (size_t)wid * D)[lane];
    float acc0 = swA * xs.x, acc1 = swB * xs.y;

    for (int c0 = 0; c0 < deg; c0 += 64) {
        int rem = deg - c0;
        int cnt = rem < 64 ? rem : 64;
        int vcol = 0;
        float vw = 0.f;
        if (lane < cnt) {
            vcol = col[off + c0 + lane];
            if (H == 1) vw = wbuf[off + c0 + lane];
        }
        auto body = [&](int j) {
            int scol = __builtin_amdgcn_readlane(vcol, j);
            float wA, wB;
            if (H == 4) {
                float2 wv = reinterpret_cast<const float2*>(wbuf)[(size_t)(off + c0 + j) * 2 + half];
                wA = wv.x; wB = wv.y;
            } else {
                wA = wB = __int_as_float(__builtin_amdgcn_readlane(__float_as_int(vw), j));
            }
            float2 xv = reinterpret_cast<const float2*>(xp2 + (size_t)scol * D)[lane];
            acc0 = fmaf(wA, xv.x, acc0);
            acc1 = fmaf(wB, xv.y, acc1);
        };
        int j = 0;
        for (; j + 4 <= cnt; j += 4) { body(j); body(j + 1); body(j + 2); body(j + 3); }
        for (; j < cnt; ++j) body(j);
    }

    float v0 = acc0 * rdA + bias[lane];
    float v1 = acc1 * rdB + bias[lane + 64];
    if (DO_ELU) {
        v0 = v0 > 0.f ? v0 : expm1f(v0);
        v1 = v1 > 0.f ? v1 : expm1f(v1);
    }
    out[(size_t)wid * D + lane] = v0;
    out[(size_t)wid * D + lane + 64] = v1;
}

// ---------------- launch ----------------
extern "C" void kernel_launch(void* const* d_in, const int* in_sizes, int n_in,
                              void* d_out, int out_size, void* d_ws, size_t ws_size,
                              hipStream_t stream) {
    (void)n_in; (void)out_size; (void)ws_size;
    const float* x   = (const float*)d_in[0];
    const void*  ei  = d_in[1];
    const float* W1  = (const float*)d_in[2];
    const float* a1s = (const float*)d_in[3];
    const float* a1d = (const float*)d_in[4];
    const float* b1  = (const float*)d_in[5];
    const float* W2  = (const float*)d_in[6];
    const float* a2s = (const float*)d_in[7];
    const float* a2d = (const float*)d_in[8];
    const float* b2  = (const float*)d_in[9];
    const int N = in_sizes[0] / D;  // 100000
    const int E = in_sizes[1] / 2;  // 1600000
    float* out = (float*)d_out;

    char* p = (char*)d_ws;
    auto alloc = [&](size_t bytes) {
        char* q = p;
        p += (bytes + 255) & ~(size_t)255;
        return q;
    };
    float* xp      = (float*)alloc((size_t)N * D * 4);   // paired layout
    float* ssrc    = (float*)alloc((size_t)N * 4 * 4);
    float* sdst    = (float*)alloc((size_t)N * 4 * 4);
    float* swbuf   = (float*)alloc((size_t)N * 4 * 4);
    float* rdbuf   = (float*)alloc((size_t)N * 4 * 4);
    int*   count   = (int*)alloc((size_t)N * 4);
    int*   cursor  = (int*)alloc((size_t)N * 4);
    int*   offsets = (int*)alloc((size_t)N * 4);
    int*   bsum    = (int*)alloc(256 * 4);
    int*   bsumex  = (int*)alloc(256 * 4);
    int*   flag    = (int*)alloc(256);
    int*   col     = (int*)alloc((size_t)E * 4);
    float* wbuf    = (float*)alloc((size_t)E * 4 * 4);   // per-edge weights (float4 for H=4)

    hipMemsetAsync(count, 0, (size_t)N * 4, stream);
    hipMemsetAsync(cursor, 0, (size_t)N * 4, stream);

    detect_i64<<<1, 64, 0, stream>>>((const unsigned int*)ei, flag);
    int eg = (E + 255) / 256;
    hist_kernel<<<eg, 256, 0, stream>>>(ei, flag, count, E);
    int B = (N + 1023) / 1024;
    reduce_1024<<<B, 256, 0, stream>>>(count, bsum, N);
    scan_partials<<<1, 256, 0, stream>>>(bsumex, bsum, B);
    scan_final<<<B, 256, 0, stream>>>(count, bsumex, offsets, N);
    scatter_kernel<<<eg, 256, 0, stream>>>(ei, flag, offsets, cursor, col, E);

    int gemmG = (N + 63) / 64;
    int nodeG = (N + 3) / 4;

    // ----- layer 1 (H=4, ELU) -----
    gemm_nn_128<<<gemmG, 256, 0, stream>>>(x, W1, xp, N);
    score_kernel<4><<<nodeG, 256, 0, stream>>>(xp, a1s, a1d, ssrc, sdst, N);
    stats_weights<4><<<nodeG, 256, 0, stream>>>(col, offsets, count, ssrc, sdst, wbuf, swbuf, rdbuf, N);
    aggregate_w<4, true><<<nodeG, 256, 0, stream>>>(col, offsets, count, xp, wbuf, swbuf, rdbuf, b1, out, N);

    // ----- layer 2 (H=1, no activation) -----
    gemm_nn_128<<<gemmG, 256, 0, stream>>>(out, W2, xp, N);
    score_kernel<1><<<nodeG, 256, 0, stream>>>(xp, a2s, a2d, ssrc, sdst, N);
    stats_weights<1><<<nodeG, 256, 0, stream>>>(col, offsets, count, ssrc, sdst, wbuf, swbuf, rdbuf, N);
    aggregate_w<1, false><<<nodeG, 256, 0, stream>>>(col, offsets, count, xp, wbuf, swbuf, rdbuf, b2, out, N);
}

// Round 13
// 655.866 us; speedup vs baseline: 1.1226x; 1.1226x over previous
//
#include <hip/hip_runtime.h>
#include <hip/hip_fp16.h>

#define D 128
#define LRELU(x) ((x) > 0.f ? (x) : 0.2f * (x))

// ---------------- edge-index width detection ----------------
__global__ void detect_i64(const unsigned int* ei, int* flag) {
    if (threadIdx.x == 0 && blockIdx.x == 0) {
        unsigned int o = 0;
#pragma unroll
        for (int k = 0; k < 64; ++k) o |= ei[2 * k + 1];
        *flag = (o == 0u) ? 1 : 0;
    }
}

__device__ __forceinline__ int load_idx(const void* ei, long long pos, int is64) {
    if (is64) return (int)((const long long*)ei)[pos];
    return ((const int*)ei)[pos];
}

// ---------------- CSR construction ----------------
__global__ void hist_kernel(const void* __restrict__ ei, const int* __restrict__ flag,
                            int* __restrict__ count, int E) {
    int e = blockIdx.x * blockDim.x + threadIdx.x;
    if (e >= E) return;
    int is64 = *flag;
    int dst = load_idx(ei, (long long)E + e, is64);
    atomicAdd(&count[dst], 1);
}

__global__ void reduce_1024(const int* __restrict__ count, int* __restrict__ bsum, int n) {
    __shared__ int sm[256];
    int t = threadIdx.x, b = blockIdx.x;
    int base = b * 1024 + t * 4;
    int s = 0;
#pragma unroll
    for (int j = 0; j < 4; ++j)
        if (base + j < n) s += count[base + j];
    sm[t] = s;
    __syncthreads();
    for (int of = 128; of >= 1; of >>= 1) {
        if (t < of) sm[t] += sm[t + of];
        __syncthreads();
    }
    if (t == 0) bsum[b] = sm[0];
}

__global__ void scan_partials(int* __restrict__ bsum_ex, const int* __restrict__ bsum, int B) {
    __shared__ int sm[256];
    int t = threadIdx.x;
    int v = (t < B) ? bsum[t] : 0;
    sm[t] = v;
    __syncthreads();
    for (int of = 1; of < 256; of <<= 1) {
        int u = (t >= of) ? sm[t - of] : 0;
        __syncthreads();
        sm[t] += u;
        __syncthreads();
    }
    if (t < B) bsum_ex[t] = sm[t] - v;
}

__global__ void scan_final(const int* __restrict__ count, const int* __restrict__ bsum_ex,
                           int* __restrict__ offsets, int n) {
    __shared__ int sm[256];
    int t = threadIdx.x, b = blockIdx.x;
    int base = b * 1024 + t * 4;
    int c[4];
#pragma unroll
    for (int j = 0; j < 4; ++j) c[j] = (base + j < n) ? count[base + j] : 0;
    int tsum = c[0] + c[1] + c[2] + c[3];
    sm[t] = tsum;
    __syncthreads();
    for (int of = 1; of < 256; of <<= 1) {
        int u = (t >= of) ? sm[t - of] : 0;
        __syncthreads();
        sm[t] += u;
        __syncthreads();
    }
    int o = bsum_ex[b] + sm[t] - tsum;
#pragma unroll
    for (int j = 0; j < 4; ++j) {
        if (base + j < n) offsets[base + j] = o;
        o += c[j];
    }
}

__global__ void scatter_kernel(const void* __restrict__ ei, const int* __restrict__ flag,
                               const int* __restrict__ offsets, int* __restrict__ cursor,
                               int* __restrict__ col, int E) {
    int e = blockIdx.x * blockDim.x + threadIdx.x;
    if (e >= E) return;
    int is64 = *flag;
    int src = load_idx(ei, e, is64);
    int dst = load_idx(ei, (long long)E + e, is64);
    int pos = offsets[dst] + atomicAdd(&cursor[dst], 1);
    col[pos] = src;
}

// ---------------- f32 GEMM: Y = X @ W, PAIRED f32 out + PAIRED fp16 copy ----------------
// Paired layout: pair p (0..63) holds (col p, col p+64). f32: 8 B/pair at
// [r*128 + 2p]. fp16: half2 at [r*64 + p]. Gather reads the fp16 copy (4 B/lane);
// score + self-loop read the exact f32 copy.
__launch_bounds__(256, 2)
__global__ void gemm_nn_128(const float* __restrict__ X, const float* __restrict__ W,
                            float* __restrict__ Yp, __half2* __restrict__ Yh, int n) {
    __shared__ float Xt[64][68];   // [k][r]
    __shared__ float Wl[64][128];  // [k][c]
    const int t = threadIdx.x;
    const int r0 = blockIdx.x * 64;
    const int rb = (t >> 4) * 4;
    const int cb = (t & 15) * 4;
    float acc[4][8] = {};
    for (int ph = 0; ph < 2; ++ph) {
#pragma unroll
        for (int it = 0; it < 4; ++it) {
            int idx = t + it * 256;
            int r = idx >> 4, kq = idx & 15;
            float4 xv = make_float4(0.f, 0.f, 0.f, 0.f);
            if (r0 + r < n)
                xv = *reinterpret_cast<const float4*>(X + (size_t)(r0 + r) * D + ph * 64 + kq * 4);
            Xt[kq * 4 + 0][r] = xv.x;
            Xt[kq * 4 + 1][r] = xv.y;
            Xt[kq * 4 + 2][r] = xv.z;
            Xt[kq * 4 + 3][r] = xv.w;
        }
#pragma unroll
        for (int it = 0; it < 8; ++it) {
            int idx = t + it * 256;
            int k = idx >> 5, c4 = idx & 31;
            *reinterpret_cast<float4*>(&Wl[k][c4 * 4]) =
                *reinterpret_cast<const float4*>(W + (size_t)(ph * 64 + k) * D + c4 * 4);
        }
        __syncthreads();
#pragma unroll 4
        for (int k = 0; k < 64; ++k) {
            float4 a = *reinterpret_cast<const float4*>(&Xt[k][rb]);
            float4 b0 = *reinterpret_cast<const float4*>(&Wl[k][cb]);
            float4 b1 = *reinterpret_cast<const float4*>(&Wl[k][cb + 64]);
            float av[4] = {a.x, a.y, a.z, a.w};
            float bv[8] = {b0.x, b0.y, b0.z, b0.w, b1.x, b1.y, b1.z, b1.w};
#pragma unroll
            for (int i = 0; i < 4; ++i)
#pragma unroll
                for (int j = 0; j < 8; ++j) acc[i][j] = fmaf(av[i], bv[j], acc[i][j]);
        }
        __syncthreads();
    }
#pragma unroll
    for (int i = 0; i < 4; ++i) {
        int row = r0 + rb + i;
        if (row < n) {
            float4 o0 = make_float4(acc[i][0], acc[i][4], acc[i][1], acc[i][5]);
            float4 o1 = make_float4(acc[i][2], acc[i][6], acc[i][3], acc[i][7]);
            *reinterpret_cast<float4*>(Yp + (size_t)row * D + 2 * cb) = o0;
            *reinterpret_cast<float4*>(Yp + (size_t)row * D + 2 * cb + 4) = o1;
            __half2 h[4];
            h[0] = __float22half2_rn(make_float2(acc[i][0], acc[i][4]));
            h[1] = __float22half2_rn(make_float2(acc[i][1], acc[i][5]));
            h[2] = __float22half2_rn(make_float2(acc[i][2], acc[i][6]));
            h[3] = __float22half2_rn(make_float2(acc[i][3], acc[i][7]));
            *reinterpret_cast<float4*>(Yh + (size_t)row * 64 + cb) =
                *reinterpret_cast<const float4*>(h);
        }
    }
}

// ---------------- attention scores from paired f32 xp ----------------
template <int H>
__launch_bounds__(256)
__global__ void score_kernel(const float* __restrict__ xp2, const float* __restrict__ a_src,
                             const float* __restrict__ a_dst, float* __restrict__ s_src,
                             float* __restrict__ s_dst, int n) {
    int wid = (blockIdx.x * 256 + threadIdx.x) >> 6;
    int lane = threadIdx.x & 63;
    if (wid >= n) return;
    float2 xv = reinterpret_cast<const float2*>(xp2 + (size_t)wid * D)[lane];
    float x0 = xv.x, x1 = xv.y;  // channels lane, lane+64
    float ps0 = x0 * a_src[lane], ps1 = x1 * a_src[lane + 64];
    float pd0 = x0 * a_dst[lane], pd1 = x1 * a_dst[lane + 64];
    if (H == 4) {
        for (int m = 16; m >= 1; m >>= 1) {
            ps0 += __shfl_xor(ps0, m);
            ps1 += __shfl_xor(ps1, m);
            pd0 += __shfl_xor(pd0, m);
            pd1 += __shfl_xor(pd1, m);
        }
        if (lane == 0) {
            s_src[wid * 4 + 0] = ps0; s_src[wid * 4 + 2] = ps1;
            s_dst[wid * 4 + 0] = pd0; s_dst[wid * 4 + 2] = pd1;
        }
        if (lane == 32) {
            s_src[wid * 4 + 1] = ps0; s_src[wid * 4 + 3] = ps1;
            s_dst[wid * 4 + 1] = pd0; s_dst[wid * 4 + 3] = pd1;
        }
    } else {
        float ps = ps0 + ps1, pd = pd0 + pd1;
        for (int m = 32; m >= 1; m >>= 1) {
            ps += __shfl_xor(ps, m);
            pd += __shfl_xor(pd, m);
        }
        if (lane == 0) { s_src[wid] = ps; s_dst[wid] = pd; }
    }
}

// ---------------- per-node softmax stats + per-edge weights ----------------
template <int H>
__launch_bounds__(256)
__global__ void stats_weights(const int* __restrict__ col, const int* __restrict__ offsets,
                              const int* __restrict__ deg_arr, const float* __restrict__ s_src,
                              const float* __restrict__ s_dst, float* __restrict__ wbuf,
                              float* __restrict__ swbuf, float* __restrict__ rdbuf, int n) {
    int wid = (blockIdx.x * 256 + threadIdx.x) >> 6;
    int lane = threadIdx.x & 63;
    if (wid >= n) return;
    int off = __builtin_amdgcn_readfirstlane(offsets[wid]);
    int deg = __builtin_amdgcn_readfirstlane(deg_arr[wid]);
    if (H == 4) {
        float4 sdv = *reinterpret_cast<const float4*>(s_dst + (size_t)wid * 4);
        float4 ssv = *reinterpret_cast<const float4*>(s_src + (size_t)wid * 4);
        float es0 = LRELU(ssv.x + sdv.x), es1 = LRELU(ssv.y + sdv.y);
        float es2 = LRELU(ssv.z + sdv.z), es3 = LRELU(ssv.w + sdv.w);
        float m0 = es0, m1 = es1, m2 = es2, m3 = es3;
        for (int i = lane; i < deg; i += 64) {
            int c = col[off + i];
            float4 q = *reinterpret_cast<const float4*>(s_src + (size_t)c * 4);
            float e0 = LRELU(q.x + sdv.x), e1 = LRELU(q.y + sdv.y);
            float e2 = LRELU(q.z + sdv.z), e3 = LRELU(q.w + sdv.w);
            m0 = fmaxf(m0, e0); m1 = fmaxf(m1, e1);
            m2 = fmaxf(m2, e2); m3 = fmaxf(m3, e3);
            *reinterpret_cast<float4*>(wbuf + (size_t)(off + i) * 4) = make_float4(e0, e2, e1, e3);
        }
        for (int s = 32; s >= 1; s >>= 1) {
            m0 = fmaxf(m0, __shfl_xor(m0, s)); m1 = fmaxf(m1, __shfl_xor(m1, s));
            m2 = fmaxf(m2, __shfl_xor(m2, s)); m3 = fmaxf(m3, __shfl_xor(m3, s));
        }
        float s0 = 0.f, s1 = 0.f, s2 = 0.f, s3 = 0.f;
        for (int i = lane; i < deg; i += 64) {
            float4 f = *reinterpret_cast<const float4*>(wbuf + (size_t)(off + i) * 4);
            float w0 = __expf(f.x - m0), w2 = __expf(f.y - m2);
            float w1 = __expf(f.z - m1), w3 = __expf(f.w - m3);
            *reinterpret_cast<float4*>(wbuf + (size_t)(off + i) * 4) = make_float4(w0, w2, w1, w3);
            s0 += w0; s1 += w1; s2 += w2; s3 += w3;
        }
        for (int s = 32; s >= 1; s >>= 1) {
            s0 += __shfl_xor(s0, s); s1 += __shfl_xor(s1, s);
            s2 += __shfl_xor(s2, s); s3 += __shfl_xor(s3, s);
        }
        if (lane == 0) {
            float sw0 = __expf(es0 - m0), sw1 = __expf(es1 - m1);
            float sw2 = __expf(es2 - m2), sw3 = __expf(es3 - m3);
            float r0 = 1.f / (s0 + sw0 + 1e-16f), r1 = 1.f / (s1 + sw1 + 1e-16f);
            float r2 = 1.f / (s2 + sw2 + 1e-16f), r3 = 1.f / (s3 + sw3 + 1e-16f);
            *reinterpret_cast<float4*>(swbuf + (size_t)wid * 4) = make_float4(sw0, sw2, sw1, sw3);
            *reinterpret_cast<float4*>(rdbuf + (size_t)wid * 4) = make_float4(r0, r2, r1, r3);
        }
    } else {
        float sd = s_dst[wid];
        float es = LRELU(s_src[wid] + sd);
        float m = es;
        for (int i = lane; i < deg; i += 64) {
            int c = col[off + i];
            float e = LRELU(s_src[c] + sd);
            m = fmaxf(m, e);
            wbuf[off + i] = e;
        }
        for (int s = 32; s >= 1; s >>= 1) m = fmaxf(m, __shfl_xor(m, s));
        float sum = 0.f;
        for (int i = lane; i < deg; i += 64) {
            float w = __expf(wbuf[off + i] - m);
            wbuf[off + i] = w;
            sum += w;
        }
        for (int s = 32; s >= 1; s >>= 1) sum += __shfl_xor(sum, s);
        if (lane == 0) {
            float sw = __expf(es - m);
            swbuf[wid] = sw;
            rdbuf[wid] = 1.f / (sum + sw + 1e-16f);
        }
    }
}

// ---------------- weighted aggregation: fp16 neighbor gather ----------------
// Wave per node; lanes own channels. Per edge: readlane col, broadcast float2 w,
// ONE half2 (4 B) xp gather -> cvt -> 2 fma. Unroll 8 for request depth.
// Self-loop from exact f32 copy; weights/softmax all f32.
template <int H, bool DO_ELU>
__launch_bounds__(256)
__global__ void aggregate_w(const int* __restrict__ col, const int* __restrict__ offsets,
                            const int* __restrict__ deg_arr, const float* __restrict__ xp2,
                            const __half2* __restrict__ xph, const float* __restrict__ wbuf,
                            const float* __restrict__ swbuf, const float* __restrict__ rdbuf,
                            const float* __restrict__ bias, float* __restrict__ out, int n) {
    int wid = (blockIdx.x * 256 + threadIdx.x) >> 6;
    int lane = threadIdx.x & 63;
    if (wid >= n) return;
    int off = __builtin_amdgcn_readfirstlane(offsets[wid]);
    int deg = __builtin_amdgcn_readfirstlane(deg_arr[wid]);
    const int half = lane >> 5;
    float swA, swB, rdA, rdB;
    if (H == 4) {
        float2 sw = reinterpret_cast<const float2*>(swbuf)[(size_t)wid * 2 + half];
        float2 rd = reinterpret_cast<const float2*>(rdbuf)[(size_t)wid * 2 + half];
        swA = sw.x; swB = sw.y; rdA = rd.x; rdB = rd.y;
    } else {
        swA = swB = swbuf[wid];
        rdA = rdB = rdbuf[wid];
    }
    float2 xs = reinterpret_cast<const float2*>(xp2 + (size_t)wid * D)[lane];
    float acc0 = swA * xs.x, acc1 = swB * xs.y;

    for (int c0 = 0; c0 < deg; c0 += 64) {
        int rem = deg - c0;
        int cnt = rem < 64 ? rem : 64;
        int vcol = 0;
        float vw = 0.f;
        if (lane < cnt) {
            vcol = col[off + c0 + lane];
            if (H == 1) vw = wbuf[off + c0 + lane];
        }
        auto body = [&](int j) {
            int scol = __builtin_amdgcn_readlane(vcol, j);
            float wA, wB;
            if (H == 4) {
                float2 wv = reinterpret_cast<const float2*>(wbuf)[(size_t)(off + c0 + j) * 2 + half];
                wA = wv.x; wB = wv.y;
            } else {
                wA = wB = __int_as_float(__builtin_amdgcn_readlane(__float_as_int(vw), j));
            }
            float2 xv = __half22float2(xph[(size_t)scol * 64 + lane]);
            acc0 = fmaf(wA, xv.x, acc0);
            acc1 = fmaf(wB, xv.y, acc1);
        };
        int j = 0;
        for (; j + 8 <= cnt; j += 8) {
            body(j); body(j + 1); body(j + 2); body(j + 3);
            body(j + 4); body(j + 5); body(j + 6); body(j + 7);
        }
        for (; j < cnt; ++j) body(j);
    }

    float v0 = acc0 * rdA + bias[lane];
    float v1 = acc1 * rdB + bias[lane + 64];
    if (DO_ELU) {
        v0 = v0 > 0.f ? v0 : expm1f(v0);
        v1 = v1 > 0.f ? v1 : expm1f(v1);
    }
    out[(size_t)wid * D + lane] = v0;
    out[(size_t)wid * D + lane + 64] = v1;
}

// ---------------- launch ----------------
extern "C" void kernel_launch(void* const* d_in, const int* in_sizes, int n_in,
                              void* d_out, int out_size, void* d_ws, size_t ws_size,
                              hipStream_t stream) {
    (void)n_in; (void)out_size; (void)ws_size;
    const float* x   = (const float*)d_in[0];
    const void*  ei  = d_in[1];
    const float* W1  = (const float*)d_in[2];
    const float* a1s = (const float*)d_in[3];
    const float* a1d = (const float*)d_in[4];
    const float* b1  = (const float*)d_in[5];
    const float* W2  = (const float*)d_in[6];
    const float* a2s = (const float*)d_in[7];
    const float* a2d = (const float*)d_in[8];
    const float* b2  = (const float*)d_in[9];
    const int N = in_sizes[0] / D;  // 100000
    const int E = in_sizes[1] / 2;  // 1600000
    float* out = (float*)d_out;

    char* p = (char*)d_ws;
    auto alloc = [&](size_t bytes) {
        char* q = p;
        p += (bytes + 255) & ~(size_t)255;
        return q;
    };
    float*   xp      = (float*)alloc((size_t)N * D * 4);     // paired f32
    __half2* xph     = (__half2*)alloc((size_t)N * 64 * 4);  // paired fp16
    float*   ssrc    = (float*)alloc((size_t)N * 4 * 4);
    float*   sdst    = (float*)alloc((size_t)N * 4 * 4);
    float*   swbuf   = (float*)alloc((size_t)N * 4 * 4);
    float*   rdbuf   = (float*)alloc((size_t)N * 4 * 4);
    int*     count   = (int*)alloc((size_t)N * 4);
    int*     cursor  = (int*)alloc((size_t)N * 4);
    int*     offsets = (int*)alloc((size_t)N * 4);
    int*     bsum    = (int*)alloc(256 * 4);
    int*     bsumex  = (int*)alloc(256 * 4);
    int*     flag    = (int*)alloc(256);
    int*     col     = (int*)alloc((size_t)E * 4);
    float*   wbuf    = (float*)alloc((size_t)E * 4 * 4);

    hipMemsetAsync(count, 0, (size_t)N * 4, stream);
    hipMemsetAsync(cursor, 0, (size_t)N * 4, stream);

    detect_i64<<<1, 64, 0, stream>>>((const unsigned int*)ei, flag);
    int eg = (E + 255) / 256;
    hist_kernel<<<eg, 256, 0, stream>>>(ei, flag, count, E);
    int B = (N + 1023) / 1024;
    reduce_1024<<<B, 256, 0, stream>>>(count, bsum, N);
    scan_partials<<<1, 256, 0, stream>>>(bsumex, bsum, B);
    scan_final<<<B, 256, 0, stream>>>(count, bsumex, offsets, N);
    scatter_kernel<<<eg, 256, 0, stream>>>(ei, flag, offsets, cursor, col, E);

    int gemmG = (N + 63) / 64;
    int nodeG = (N + 3) / 4;

    // ----- layer 1 (H=4, ELU) -----
    gemm_nn_128<<<gemmG, 256, 0, stream>>>(x, W1, xp, xph, N);
    score_kernel<4><<<nodeG, 256, 0, stream>>>(xp, a1s, a1d, ssrc, sdst, N);
    stats_weights<4><<<nodeG, 256, 0, stream>>>(col, offsets, count, ssrc, sdst, wbuf, swbuf, rdbuf, N);
    aggregate_w<4, true><<<nodeG, 256, 0, stream>>>(col, offsets, count, xp, xph, wbuf, swbuf, rdbuf, b1, out, N);

    // ----- layer 2 (H=1, no activation) -----
    gemm_nn_128<<<gemmG, 256, 0, stream>>>(out, W2, xp, xph, N);
    score_kernel<1><<<nodeG, 256, 0, stream>>>(xp, a2s, a2d, ssrc, sdst, N);
    stats_weights<1><<<nodeG, 256, 0, stream>>>(col, offsets, count, ssrc, sdst, wbuf, swbuf, rdbuf, N);
    aggregate_w<1, false><<<nodeG, 256, 0, stream>>>(col, offsets, count, xp, xph, wbuf, swbuf, rdbuf, b2, out, N);
}

// Round 14
// 607.344 us; speedup vs baseline: 1.2123x; 1.0799x over previous
//
#include <hip/hip_runtime.h>
#include <hip/hip_fp16.h>

#define D 128
#define LRELU(x) ((x) > 0.f ? (x) : 0.2f * (x))

// ---------------- edge-index width detection ----------------
__global__ void detect_i64(const unsigned int* ei, int* flag) {
    if (threadIdx.x == 0 && blockIdx.x == 0) {
        unsigned int o = 0;
#pragma unroll
        for (int k = 0; k < 64; ++k) o |= ei[2 * k + 1];
        *flag = (o == 0u) ? 1 : 0;
    }
}

__device__ __forceinline__ int load_idx(const void* ei, long long pos, int is64) {
    if (is64) return (int)((const long long*)ei)[pos];
    return ((const int*)ei)[pos];
}

// ---------------- CSR construction ----------------
// hist also emits each edge's rank within its dst segment (atomicAdd return),
// so the scatter pass needs NO atomics (round-13: scatter was atomic-latency
// bound at ~100 us with cursor atomics).
__global__ void hist_kernel(const void* __restrict__ ei, const int* __restrict__ flag,
                            int* __restrict__ count, int* __restrict__ rank, int E) {
    int e = blockIdx.x * blockDim.x + threadIdx.x;
    if (e >= E) return;
    int is64 = *flag;
    int dst = load_idx(ei, (long long)E + e, is64);
    rank[e] = atomicAdd(&count[dst], 1);
}

__global__ void reduce_1024(const int* __restrict__ count, int* __restrict__ bsum, int n) {
    __shared__ int sm[256];
    int t = threadIdx.x, b = blockIdx.x;
    int base = b * 1024 + t * 4;
    int s = 0;
#pragma unroll
    for (int j = 0; j < 4; ++j)
        if (base + j < n) s += count[base + j];
    sm[t] = s;
    __syncthreads();
    for (int of = 128; of >= 1; of >>= 1) {
        if (t < of) sm[t] += sm[t + of];
        __syncthreads();
    }
    if (t == 0) bsum[b] = sm[0];
}

__global__ void scan_partials(int* __restrict__ bsum_ex, const int* __restrict__ bsum, int B) {
    __shared__ int sm[256];
    int t = threadIdx.x;
    int v = (t < B) ? bsum[t] : 0;
    sm[t] = v;
    __syncthreads();
    for (int of = 1; of < 256; of <<= 1) {
        int u = (t >= of) ? sm[t - of] : 0;
        __syncthreads();
        sm[t] += u;
        __syncthreads();
    }
    if (t < B) bsum_ex[t] = sm[t] - v;
}

__global__ void scan_final(const int* __restrict__ count, const int* __restrict__ bsum_ex,
                           int* __restrict__ offsets, int n) {
    __shared__ int sm[256];
    int t = threadIdx.x, b = blockIdx.x;
    int base = b * 1024 + t * 4;
    int c[4];
#pragma unroll
    for (int j = 0; j < 4; ++j) c[j] = (base + j < n) ? count[base + j] : 0;
    int tsum = c[0] + c[1] + c[2] + c[3];
    sm[t] = tsum;
    __syncthreads();
    for (int of = 1; of < 256; of <<= 1) {
        int u = (t >= of) ? sm[t - of] : 0;
        __syncthreads();
        sm[t] += u;
        __syncthreads();
    }
    int o = bsum_ex[b] + sm[t] - tsum;
#pragma unroll
    for (int j = 0; j < 4; ++j) {
        if (base + j < n) offsets[base + j] = o;
        o += c[j];
    }
}

// atomic-free scatter: pos = offsets[dst] + rank[e]
__global__ void scatter_kernel(const void* __restrict__ ei, const int* __restrict__ flag,
                               const int* __restrict__ offsets, const int* __restrict__ rank,
                               int* __restrict__ col, int E) {
    int e = blockIdx.x * blockDim.x + threadIdx.x;
    if (e >= E) return;
    int is64 = *flag;
    int src = load_idx(ei, e, is64);
    int dst = load_idx(ei, (long long)E + e, is64);
    col[offsets[dst] + rank[e]] = src;
}

// ---------------- f32 GEMM: Y = X @ W, PAIRED f32 out + PAIRED fp16 copy ----------------
// Paired layout: pair p (0..63) holds (col p, col p+64). f32: 8 B/pair at
// [r*128 + 2p]. fp16: half2 at [r*64 + p]. Gather reads the fp16 copy (4 B/lane);
// score + self-loop read the exact f32 copy.
__launch_bounds__(256, 2)
__global__ void gemm_nn_128(const float* __restrict__ X, const float* __restrict__ W,
                            float* __restrict__ Yp, __half2* __restrict__ Yh, int n) {
    __shared__ float Xt[64][68];   // [k][r]
    __shared__ float Wl[64][128];  // [k][c]
    const int t = threadIdx.x;
    const int r0 = blockIdx.x * 64;
    const int rb = (t >> 4) * 4;
    const int cb = (t & 15) * 4;
    float acc[4][8] = {};
    for (int ph = 0; ph < 2; ++ph) {
#pragma unroll
        for (int it = 0; it < 4; ++it) {
            int idx = t + it * 256;
            int r = idx >> 4, kq = idx & 15;
            float4 xv = make_float4(0.f, 0.f, 0.f, 0.f);
            if (r0 + r < n)
                xv = *reinterpret_cast<const float4*>(X + (size_t)(r0 + r) * D + ph * 64 + kq * 4);
            Xt[kq * 4 + 0][r] = xv.x;
            Xt[kq * 4 + 1][r] = xv.y;
            Xt[kq * 4 + 2][r] = xv.z;
            Xt[kq * 4 + 3][r] = xv.w;
        }
#pragma unroll
        for (int it = 0; it < 8; ++it) {
            int idx = t + it * 256;
            int k = idx >> 5, c4 = idx & 31;
            *reinterpret_cast<float4*>(&Wl[k][c4 * 4]) =
                *reinterpret_cast<const float4*>(W + (size_t)(ph * 64 + k) * D + c4 * 4);
        }
        __syncthreads();
#pragma unroll 4
        for (int k = 0; k < 64; ++k) {
            float4 a = *reinterpret_cast<const float4*>(&Xt[k][rb]);
            float4 b0 = *reinterpret_cast<const float4*>(&Wl[k][cb]);
            float4 b1 = *reinterpret_cast<const float4*>(&Wl[k][cb + 64]);
            float av[4] = {a.x, a.y, a.z, a.w};
            float bv[8] = {b0.x, b0.y, b0.z, b0.w, b1.x, b1.y, b1.z, b1.w};
#pragma unroll
            for (int i = 0; i < 4; ++i)
#pragma unroll
                for (int j = 0; j < 8; ++j) acc[i][j] = fmaf(av[i], bv[j], acc[i][j]);
        }
        __syncthreads();
    }
#pragma unroll
    for (int i = 0; i < 4; ++i) {
        int row = r0 + rb + i;
        if (row < n) {
            float4 o0 = make_float4(acc[i][0], acc[i][4], acc[i][1], acc[i][5]);
            float4 o1 = make_float4(acc[i][2], acc[i][6], acc[i][3], acc[i][7]);
            *reinterpret_cast<float4*>(Yp + (size_t)row * D + 2 * cb) = o0;
            *reinterpret_cast<float4*>(Yp + (size_t)row * D + 2 * cb + 4) = o1;
            __half2 h[4];
            h[0] = __float22half2_rn(make_float2(acc[i][0], acc[i][4]));
            h[1] = __float22half2_rn(make_float2(acc[i][1], acc[i][5]));
            h[2] = __float22half2_rn(make_float2(acc[i][2], acc[i][6]));
            h[3] = __float22half2_rn(make_float2(acc[i][3], acc[i][7]));
            *reinterpret_cast<float4*>(Yh + (size_t)row * 64 + cb) =
                *reinterpret_cast<const float4*>(h);
        }
    }
}

// ---------------- attention scores from paired f32 xp ----------------
template <int H>
__launch_bounds__(256)
__global__ void score_kernel(const float* __restrict__ xp2, const float* __restrict__ a_src,
                             const float* __restrict__ a_dst, float* __restrict__ s_src,
                             float* __restrict__ s_dst, int n) {
    int wid = (blockIdx.x * 256 + threadIdx.x) >> 6;
    int lane = threadIdx.x & 63;
    if (wid >= n) return;
    float2 xv = reinterpret_cast<const float2*>(xp2 + (size_t)wid * D)[lane];
    float x0 = xv.x, x1 = xv.y;  // channels lane, lane+64
    float ps0 = x0 * a_src[lane], ps1 = x1 * a_src[lane + 64];
    float pd0 = x0 * a_dst[lane], pd1 = x1 * a_dst[lane + 64];
    if (H == 4) {
        for (int m = 16; m >= 1; m >>= 1) {
            ps0 += __shfl_xor(ps0, m);
            ps1 += __shfl_xor(ps1, m);
            pd0 += __shfl_xor(pd0, m);
            pd1 += __shfl_xor(pd1, m);
        }
        if (lane == 0) {
            s_src[wid * 4 + 0] = ps0; s_src[wid * 4 + 2] = ps1;
            s_dst[wid * 4 + 0] = pd0; s_dst[wid * 4 + 2] = pd1;
        }
        if (lane == 32) {
            s_src[wid * 4 + 1] = ps0; s_src[wid * 4 + 3] = ps1;
            s_dst[wid * 4 + 1] = pd0; s_dst[wid * 4 + 3] = pd1;
        }
    } else {
        float ps = ps0 + ps1, pd = pd0 + pd1;
        for (int m = 32; m >= 1; m >>= 1) {
            ps += __shfl_xor(ps, m);
            pd += __shfl_xor(pd, m);
        }
        if (lane == 0) { s_src[wid] = ps; s_dst[wid] = pd; }
    }
}

// ---------------- per-node softmax stats + per-edge weights ----------------
template <int H>
__launch_bounds__(256)
__global__ void stats_weights(const int* __restrict__ col, const int* __restrict__ offsets,
                              const int* __restrict__ deg_arr, const float* __restrict__ s_src,
                              const float* __restrict__ s_dst, float* __restrict__ wbuf,
                              float* __restrict__ swbuf, float* __restrict__ rdbuf, int n) {
    int wid = (blockIdx.x * 256 + threadIdx.x) >> 6;
    int lane = threadIdx.x & 63;
    if (wid >= n) return;
    int off = __builtin_amdgcn_readfirstlane(offsets[wid]);
    int deg = __builtin_amdgcn_readfirstlane(deg_arr[wid]);
    if (H == 4) {
        float4 sdv = *reinterpret_cast<const float4*>(s_dst + (size_t)wid * 4);
        float4 ssv = *reinterpret_cast<const float4*>(s_src + (size_t)wid * 4);
        float es0 = LRELU(ssv.x + sdv.x), es1 = LRELU(ssv.y + sdv.y);
        float es2 = LRELU(ssv.z + sdv.z), es3 = LRELU(ssv.w + sdv.w);
        float m0 = es0, m1 = es1, m2 = es2, m3 = es3;
        for (int i = lane; i < deg; i += 64) {
            int c = col[off + i];
            float4 q = *reinterpret_cast<const float4*>(s_src + (size_t)c * 4);
            float e0 = LRELU(q.x + sdv.x), e1 = LRELU(q.y + sdv.y);
            float e2 = LRELU(q.z + sdv.z), e3 = LRELU(q.w + sdv.w);
            m0 = fmaxf(m0, e0); m1 = fmaxf(m1, e1);
            m2 = fmaxf(m2, e2); m3 = fmaxf(m3, e3);
            *reinterpret_cast<float4*>(wbuf + (size_t)(off + i) * 4) = make_float4(e0, e2, e1, e3);
        }
        for (int s = 32; s >= 1; s >>= 1) {
            m0 = fmaxf(m0, __shfl_xor(m0, s)); m1 = fmaxf(m1, __shfl_xor(m1, s));
            m2 = fmaxf(m2, __shfl_xor(m2, s)); m3 = fmaxf(m3, __shfl_xor(m3, s));
        }
        float s0 = 0.f, s1 = 0.f, s2 = 0.f, s3 = 0.f;
        for (int i = lane; i < deg; i += 64) {
            float4 f = *reinterpret_cast<const float4*>(wbuf + (size_t)(off + i) * 4);
            float w0 = __expf(f.x - m0), w2 = __expf(f.y - m2);
            float w1 = __expf(f.z - m1), w3 = __expf(f.w - m3);
            *reinterpret_cast<float4*>(wbuf + (size_t)(off + i) * 4) = make_float4(w0, w2, w1, w3);
            s0 += w0; s1 += w1; s2 += w2; s3 += w3;
        }
        for (int s = 32; s >= 1; s >>= 1) {
            s0 += __shfl_xor(s0, s); s1 += __shfl_xor(s1, s);
            s2 += __shfl_xor(s2, s); s3 += __shfl_xor(s3, s);
        }
        if (lane == 0) {
            float sw0 = __expf(es0 - m0), sw1 = __expf(es1 - m1);
            float sw2 = __expf(es2 - m2), sw3 = __expf(es3 - m3);
            float r0 = 1.f / (s0 + sw0 + 1e-16f), r1 = 1.f / (s1 + sw1 + 1e-16f);
            float r2 = 1.f / (s2 + sw2 + 1e-16f), r3 = 1.f / (s3 + sw3 + 1e-16f);
            *reinterpret_cast<float4*>(swbuf + (size_t)wid * 4) = make_float4(sw0, sw2, sw1, sw3);
            *reinterpret_cast<float4*>(rdbuf + (size_t)wid * 4) = make_float4(r0, r2, r1, r3);
        }
    } else {
        float sd = s_dst[wid];
        float es = LRELU(s_src[wid] + sd);
        float m = es;
        for (int i = lane; i < deg; i += 64) {
            int c = col[off + i];
            float e = LRELU(s_src[c] + sd);
            m = fmaxf(m, e);
            wbuf[off + i] = e;
        }
        for (int s = 32; s >= 1; s >>= 1) m = fmaxf(m, __shfl_xor(m, s));
        float sum = 0.f;
        for (int i = lane; i < deg; i += 64) {
            float w = __expf(wbuf[off + i] - m);
            wbuf[off + i] = w;
            sum += w;
        }
        for (int s = 32; s >= 1; s >>= 1) sum += __shfl_xor(sum, s);
        if (lane == 0) {
            float sw = __expf(es - m);
            swbuf[wid] = sw;
            rdbuf[wid] = 1.f / (sum + sw + 1e-16f);
        }
    }
}

// ---------------- weighted aggregation: fp16 neighbor gather ----------------
// Wave per node; lanes own channels. Per edge: readlane col, broadcast float2 w,
// ONE half2 (4 B) xp gather -> cvt -> 2 fma. Unroll 8 for request depth.
// Self-loop from exact f32 copy; weights/softmax all f32.
template <int H, bool DO_ELU>
__launch_bounds__(256)
__global__ void aggregate_w(const int* __restrict__ col, const int* __restrict__ offsets,
                            const int* __restrict__ deg_arr, const float* __restrict__ xp2,
                            const __half2* __restrict__ xph, const float* __restrict__ wbuf,
                            const float* __restrict__ swbuf, const float* __restrict__ rdbuf,
                            const float* __restrict__ bias, float* __restrict__ out, int n) {
    int wid = (blockIdx.x * 256 + threadIdx.x) >> 6;
    int lane = threadIdx.x & 63;
    if (wid >= n) return;
    int off = __builtin_amdgcn_readfirstlane(offsets[wid]);
    int deg = __builtin_amdgcn_readfirstlane(deg_arr[wid]);
    const int half = lane >> 5;
    float swA, swB, rdA, rdB;
    if (H == 4) {
        float2 sw = reinterpret_cast<const float2*>(swbuf)[(size_t)wid * 2 + half];
        float2 rd = reinterpret_cast<const float2*>(rdbuf)[(size_t)wid * 2 + half];
        swA = sw.x; swB = sw.y; rdA = rd.x; rdB = rd.y;
    } else {
        swA = swB = swbuf[wid];
        rdA = rdB = rdbuf[wid];
    }
    float2 xs = reinterpret_cast<const float2*>(xp2 + (size_t)wid * D)[lane];
    float acc0 = swA * xs.x, acc1 = swB * xs.y;

    for (int c0 = 0; c0 < deg; c0 += 64) {
        int rem = deg - c0;
        int cnt = rem < 64 ? rem : 64;
        int vcol = 0;
        float vw = 0.f;
        if (lane < cnt) {
            vcol = col[off + c0 + lane];
            if (H == 1) vw = wbuf[off + c0 + lane];
        }
        auto body = [&](int j) {
            int scol = __builtin_amdgcn_readlane(vcol, j);
            float wA, wB;
            if (H == 4) {
                float2 wv = reinterpret_cast<const float2*>(wbuf)[(size_t)(off + c0 + j) * 2 + half];
                wA = wv.x; wB = wv.y;
            } else {
                wA = wB = __int_as_float(__builtin_amdgcn_readlane(__float_as_int(vw), j));
            }
            float2 xv = __half22float2(xph[(size_t)scol * 64 + lane]);
            acc0 = fmaf(wA, xv.x, acc0);
            acc1 = fmaf(wB, xv.y, acc1);
        };
        int j = 0;
        for (; j + 8 <= cnt; j += 8) {
            body(j); body(j + 1); body(j + 2); body(j + 3);
            body(j + 4); body(j + 5); body(j + 6); body(j + 7);
        }
        for (; j < cnt; ++j) body(j);
    }

    float v0 = acc0 * rdA + bias[lane];
    float v1 = acc1 * rdB + bias[lane + 64];
    if (DO_ELU) {
        v0 = v0 > 0.f ? v0 : expm1f(v0);
        v1 = v1 > 0.f ? v1 : expm1f(v1);
    }
    out[(size_t)wid * D + lane] = v0;
    out[(size_t)wid * D + lane + 64] = v1;
}

// ---------------- launch ----------------
extern "C" void kernel_launch(void* const* d_in, const int* in_sizes, int n_in,
                              void* d_out, int out_size, void* d_ws, size_t ws_size,
                              hipStream_t stream) {
    (void)n_in; (void)out_size; (void)ws_size;
    const float* x   = (const float*)d_in[0];
    const void*  ei  = d_in[1];
    const float* W1  = (const float*)d_in[2];
    const float* a1s = (const float*)d_in[3];
    const float* a1d = (const float*)d_in[4];
    const float* b1  = (const float*)d_in[5];
    const float* W2  = (const float*)d_in[6];
    const float* a2s = (const float*)d_in[7];
    const float* a2d = (const float*)d_in[8];
    const float* b2  = (const float*)d_in[9];
    const int N = in_sizes[0] / D;  // 100000
    const int E = in_sizes[1] / 2;  // 1600000
    float* out = (float*)d_out;

    char* p = (char*)d_ws;
    auto alloc = [&](size_t bytes) {
        char* q = p;
        p += (bytes + 255) & ~(size_t)255;
        return q;
    };
    float*   xp      = (float*)alloc((size_t)N * D * 4);     // paired f32
    __half2* xph     = (__half2*)alloc((size_t)N * 64 * 4);  // paired fp16
    float*   ssrc    = (float*)alloc((size_t)N * 4 * 4);
    float*   sdst    = (float*)alloc((size_t)N * 4 * 4);
    float*   swbuf   = (float*)alloc((size_t)N * 4 * 4);
    float*   rdbuf   = (float*)alloc((size_t)N * 4 * 4);
    int*     count   = (int*)alloc((size_t)N * 4);
    int*     offsets = (int*)alloc((size_t)N * 4);
    int*     bsum    = (int*)alloc(256 * 4);
    int*     bsumex  = (int*)alloc(256 * 4);
    int*     flag    = (int*)alloc(256);
    int*     col     = (int*)alloc((size_t)E * 4);
    int*     rank    = (int*)alloc((size_t)E * 4);
    float*   wbuf    = (float*)alloc((size_t)E * 4 * 4);

    hipMemsetAsync(count, 0, (size_t)N * 4, stream);

    detect_i64<<<1, 64, 0, stream>>>((const unsigned int*)ei, flag);
    int eg = (E + 255) / 256;
    hist_kernel<<<eg, 256, 0, stream>>>(ei, flag, count, rank, E);
    int B = (N + 1023) / 1024;
    reduce_1024<<<B, 256, 0, stream>>>(count, bsum, N);
    scan_partials<<<1, 256, 0, stream>>>(bsumex, bsum, B);
    scan_final<<<B, 256, 0, stream>>>(count, bsumex, offsets, N);
    scatter_kernel<<<eg, 256, 0, stream>>>(ei, flag, offsets, rank, col, E);

    int gemmG = (N + 63) / 64;
    int nodeG = (N + 3) / 4;

    // ----- layer 1 (H=4, ELU) -----
    gemm_nn_128<<<gemmG, 256, 0, stream>>>(x, W1, xp, xph, N);
    score_kernel<4><<<nodeG, 256, 0, stream>>>(xp, a1s, a1d, ssrc, sdst, N);
    stats_weights<4><<<nodeG, 256, 0, stream>>>(col, offsets, count, ssrc, sdst, wbuf, swbuf, rdbuf, N);
    aggregate_w<4, true><<<nodeG, 256, 0, stream>>>(col, offsets, count, xp, xph, wbuf, swbuf, rdbuf, b1, out, N);

    // ----- layer 2 (H=1, no activation) -----
    gemm_nn_128<<<gemmG, 256, 0, stream>>>(out, W2, xp, xph, N);
    score_kernel<1><<<nodeG, 256, 0, stream>>>(xp, a2s, a2d, ssrc, sdst, N);
    stats_weights<1><<<nodeG, 256, 0, stream>>>(col, offsets, count, ssrc, sdst, wbuf, swbuf, rdbuf, N);
    aggregate_w<1, false><<<nodeG, 256, 0, stream>>>(col, offsets, count, xp, xph, wbuf, swbuf, rdbuf, b2, out, N);
}

// Round 15
// 541.646 us; speedup vs baseline: 1.3594x; 1.1213x over previous
//
#include <hip/hip_runtime.h>
#include <hip/hip_fp16.h>

#define D 128
#define LRELU(x) ((x) > 0.f ? (x) : 0.2f * (x))

// ---------------- edge-index width detection ----------------
__global__ void detect_i64(const unsigned int* ei, int* flag) {
    if (threadIdx.x == 0 && blockIdx.x == 0) {
        unsigned int o = 0;
#pragma unroll
        for (int k = 0; k < 64; ++k) o |= ei[2 * k + 1];
        *flag = (o == 0u) ? 1 : 0;
    }
}

__device__ __forceinline__ int load_idx(const void* ei, long long pos, int is64) {
    if (is64) return (int)((const long long*)ei)[pos];
    return ((const int*)ei)[pos];
}

// ---------------- CSR construction ----------------
__global__ void hist_kernel(const void* __restrict__ ei, const int* __restrict__ flag,
                            int* __restrict__ count, int* __restrict__ rank, int E) {
    int e = blockIdx.x * blockDim.x + threadIdx.x;
    if (e >= E) return;
    int is64 = *flag;
    int dst = load_idx(ei, (long long)E + e, is64);
    rank[e] = atomicAdd(&count[dst], 1);
}

__global__ void reduce_1024(const int* __restrict__ count, int* __restrict__ bsum, int n) {
    __shared__ int sm[256];
    int t = threadIdx.x, b = blockIdx.x;
    int base = b * 1024 + t * 4;
    int s = 0;
#pragma unroll
    for (int j = 0; j < 4; ++j)
        if (base + j < n) s += count[base + j];
    sm[t] = s;
    __syncthreads();
    for (int of = 128; of >= 1; of >>= 1) {
        if (t < of) sm[t] += sm[t + of];
        __syncthreads();
    }
    if (t == 0) bsum[b] = sm[0];
}

__global__ void scan_partials(int* __restrict__ bsum_ex, const int* __restrict__ bsum, int B) {
    __shared__ int sm[256];
    int t = threadIdx.x;
    int v = (t < B) ? bsum[t] : 0;
    sm[t] = v;
    __syncthreads();
    for (int of = 1; of < 256; of <<= 1) {
        int u = (t >= of) ? sm[t - of] : 0;
        __syncthreads();
        sm[t] += u;
        __syncthreads();
    }
    if (t < B) bsum_ex[t] = sm[t] - v;
}

__global__ void scan_final(const int* __restrict__ count, const int* __restrict__ bsum_ex,
                           int* __restrict__ offsets, int n) {
    __shared__ int sm[256];
    int t = threadIdx.x, b = blockIdx.x;
    int base = b * 1024 + t * 4;
    int c[4];
#pragma unroll
    for (int j = 0; j < 4; ++j) c[j] = (base + j < n) ? count[base + j] : 0;
    int tsum = c[0] + c[1] + c[2] + c[3];
    sm[t] = tsum;
    __syncthreads();
    for (int of = 1; of < 256; of <<= 1) {
        int u = (t >= of) ? sm[t - of] : 0;
        __syncthreads();
        sm[t] += u;
        __syncthreads();
    }
    int o = bsum_ex[b] + sm[t] - tsum;
#pragma unroll
    for (int j = 0; j < 4; ++j) {
        if (base + j < n) offsets[base + j] = o;
        o += c[j];
    }
}

// atomic-free scatter: pos = offsets[dst] + rank[e]
__global__ void scatter_kernel(const void* __restrict__ ei, const int* __restrict__ flag,
                               const int* __restrict__ offsets, const int* __restrict__ rank,
                               int* __restrict__ col, int E) {
    int e = blockIdx.x * blockDim.x + threadIdx.x;
    if (e >= E) return;
    int is64 = *flag;
    int src = load_idx(ei, e, is64);
    int dst = load_idx(ei, (long long)E + e, is64);
    col[offsets[dst] + rank[e]] = src;
}

// ---------------- f32 GEMM: Y = X @ W, PAIRED f32 out + PAIRED fp16 copy ----------------
__launch_bounds__(256, 2)
__global__ void gemm_nn_128(const float* __restrict__ X, const float* __restrict__ W,
                            float* __restrict__ Yp, __half2* __restrict__ Yh, int n) {
    __shared__ float Xt[64][68];   // [k][r]
    __shared__ float Wl[64][128];  // [k][c]
    const int t = threadIdx.x;
    const int r0 = blockIdx.x * 64;
    const int rb = (t >> 4) * 4;
    const int cb = (t & 15) * 4;
    float acc[4][8] = {};
    for (int ph = 0; ph < 2; ++ph) {
#pragma unroll
        for (int it = 0; it < 4; ++it) {
            int idx = t + it * 256;
            int r = idx >> 4, kq = idx & 15;
            float4 xv = make_float4(0.f, 0.f, 0.f, 0.f);
            if (r0 + r < n)
                xv = *reinterpret_cast<const float4*>(X + (size_t)(r0 + r) * D + ph * 64 + kq * 4);
            Xt[kq * 4 + 0][r] = xv.x;
            Xt[kq * 4 + 1][r] = xv.y;
            Xt[kq * 4 + 2][r] = xv.z;
            Xt[kq * 4 + 3][r] = xv.w;
        }
#pragma unroll
        for (int it = 0; it < 8; ++it) {
            int idx = t + it * 256;
            int k = idx >> 5, c4 = idx & 31;
            *reinterpret_cast<float4*>(&Wl[k][c4 * 4]) =
                *reinterpret_cast<const float4*>(W + (size_t)(ph * 64 + k) * D + c4 * 4);
        }
        __syncthreads();
#pragma unroll 4
        for (int k = 0; k < 64; ++k) {
            float4 a = *reinterpret_cast<const float4*>(&Xt[k][rb]);
            float4 b0 = *reinterpret_cast<const float4*>(&Wl[k][cb]);
            float4 b1 = *reinterpret_cast<const float4*>(&Wl[k][cb + 64]);
            float av[4] = {a.x, a.y, a.z, a.w};
            float bv[8] = {b0.x, b0.y, b0.z, b0.w, b1.x, b1.y, b1.z, b1.w};
#pragma unroll
            for (int i = 0; i < 4; ++i)
#pragma unroll
                for (int j = 0; j < 8; ++j) acc[i][j] = fmaf(av[i], bv[j], acc[i][j]);
        }
        __syncthreads();
    }
#pragma unroll
    for (int i = 0; i < 4; ++i) {
        int row = r0 + rb + i;
        if (row < n) {
            float4 o0 = make_float4(acc[i][0], acc[i][4], acc[i][1], acc[i][5]);
            float4 o1 = make_float4(acc[i][2], acc[i][6], acc[i][3], acc[i][7]);
            *reinterpret_cast<float4*>(Yp + (size_t)row * D + 2 * cb) = o0;
            *reinterpret_cast<float4*>(Yp + (size_t)row * D + 2 * cb + 4) = o1;
            __half2 h[4];
            h[0] = __float22half2_rn(make_float2(acc[i][0], acc[i][4]));
            h[1] = __float22half2_rn(make_float2(acc[i][1], acc[i][5]));
            h[2] = __float22half2_rn(make_float2(acc[i][2], acc[i][6]));
            h[3] = __float22half2_rn(make_float2(acc[i][3], acc[i][7]));
            *reinterpret_cast<float4*>(Yh + (size_t)row * 64 + cb) =
                *reinterpret_cast<const float4*>(h);
        }
    }
}

// ---------------- attention scores from paired f32 xp ----------------
template <int H>
__launch_bounds__(256)
__global__ void score_kernel(const float* __restrict__ xp2, const float* __restrict__ a_src,
                             const float* __restrict__ a_dst, float* __restrict__ s_src,
                             float* __restrict__ s_dst, int n) {
    int wid = (blockIdx.x * 256 + threadIdx.x) >> 6;
    int lane = threadIdx.x & 63;
    if (wid >= n) return;
    float2 xv = reinterpret_cast<const float2*>(xp2 + (size_t)wid * D)[lane];
    float x0 = xv.x, x1 = xv.y;
    float ps0 = x0 * a_src[lane], ps1 = x1 * a_src[lane + 64];
    float pd0 = x0 * a_dst[lane], pd1 = x1 * a_dst[lane + 64];
    if (H == 4) {
        for (int m = 16; m >= 1; m >>= 1) {
            ps0 += __shfl_xor(ps0, m);
            ps1 += __shfl_xor(ps1, m);
            pd0 += __shfl_xor(pd0, m);
            pd1 += __shfl_xor(pd1, m);
        }
        if (lane == 0) {
            s_src[wid * 4 + 0] = ps0; s_src[wid * 4 + 2] = ps1;
            s_dst[wid * 4 + 0] = pd0; s_dst[wid * 4 + 2] = pd1;
        }
        if (lane == 32) {
            s_src[wid * 4 + 1] = ps0; s_src[wid * 4 + 3] = ps1;
            s_dst[wid * 4 + 1] = pd0; s_dst[wid * 4 + 3] = pd1;
        }
    } else {
        float ps = ps0 + ps1, pd = pd0 + pd1;
        for (int m = 32; m >= 1; m >>= 1) {
            ps += __shfl_xor(ps, m);
            pd += __shfl_xor(pd, m);
        }
        if (lane == 0) { s_src[wid] = ps; s_dst[wid] = pd; }
    }
}

__device__ __forceinline__ float rl_f(float v, int j) {
    return __int_as_float(__builtin_amdgcn_readlane(__float_as_int(v), j));
}

// ---------------- fused softmax + aggregation, wave per node ----------------
// Pass A (lanes own edges): gather s_src[col], e=lrelu, shfl-reduce max.
// Pass B (per 64-edge chunk): recompute w=exp(e-m) in REGISTERS (<=H exp/lane),
// inner loop broadcasts col+weights via readlane (no wbuf memory at all),
// gathers fp16 row, fma. wsum reduced at end -> rd applied once.
template <int H, bool DO_ELU>
__launch_bounds__(256)
__global__ void fused_node(const int* __restrict__ col, const int* __restrict__ offsets,
                           const int* __restrict__ deg_arr, const float* __restrict__ xp2,
                           const __half2* __restrict__ xph, const float* __restrict__ s_src,
                           const float* __restrict__ s_dst, const float* __restrict__ bias,
                           float* __restrict__ out, int n) {
    int wid = (blockIdx.x * 256 + threadIdx.x) >> 6;
    int lane = threadIdx.x & 63;
    if (wid >= n) return;
    int off = __builtin_amdgcn_readfirstlane(offsets[wid]);
    int deg = __builtin_amdgcn_readfirstlane(deg_arr[wid]);
    const int hf = lane >> 5;

    if (H == 4) {
        float4 sdv = *reinterpret_cast<const float4*>(s_dst + (size_t)wid * 4);
        float4 ssv = *reinterpret_cast<const float4*>(s_src + (size_t)wid * 4);
        float es0 = LRELU(ssv.x + sdv.x), es1 = LRELU(ssv.y + sdv.y);
        float es2 = LRELU(ssv.z + sdv.z), es3 = LRELU(ssv.w + sdv.w);
        float m0 = es0, m1 = es1, m2 = es2, m3 = es3;
        // pass A: segment max
        for (int i = lane; i < deg; i += 64) {
            int c = col[off + i];
            float4 q = *reinterpret_cast<const float4*>(s_src + (size_t)c * 4);
            m0 = fmaxf(m0, LRELU(q.x + sdv.x));
            m1 = fmaxf(m1, LRELU(q.y + sdv.y));
            m2 = fmaxf(m2, LRELU(q.z + sdv.z));
            m3 = fmaxf(m3, LRELU(q.w + sdv.w));
        }
        for (int s = 32; s >= 1; s >>= 1) {
            m0 = fmaxf(m0, __shfl_xor(m0, s)); m1 = fmaxf(m1, __shfl_xor(m1, s));
            m2 = fmaxf(m2, __shfl_xor(m2, s)); m3 = fmaxf(m3, __shfl_xor(m3, s));
        }
        float sw0 = __expf(es0 - m0), sw1 = __expf(es1 - m1);
        float sw2 = __expf(es2 - m2), sw3 = __expf(es3 - m3);
        // acc init with self term (exact f32 row)
        float2 xs = reinterpret_cast<const float2*>(xp2 + (size_t)wid * D)[lane];
        float acc0 = (hf ? sw1 : sw0) * xs.x;
        float acc1 = (hf ? sw3 : sw2) * xs.y;
        float t0 = 0.f, t1 = 0.f, t2 = 0.f, t3 = 0.f;  // wsum
        // pass B
        for (int c0 = 0; c0 < deg; c0 += 64) {
            int rem = deg - c0;
            int cnt = rem < 64 ? rem : 64;
            int vcol = 0;
            float w0 = 0.f, w1 = 0.f, w2 = 0.f, w3 = 0.f;
            if (lane < cnt) {
                vcol = col[off + c0 + lane];
                float4 q = *reinterpret_cast<const float4*>(s_src + (size_t)vcol * 4);
                w0 = __expf(LRELU(q.x + sdv.x) - m0);
                w1 = __expf(LRELU(q.y + sdv.y) - m1);
                w2 = __expf(LRELU(q.z + sdv.z) - m2);
                w3 = __expf(LRELU(q.w + sdv.w) - m3);
                t0 += w0; t1 += w1; t2 += w2; t3 += w3;
            }
            auto body = [&](int j) {
                int scol = __builtin_amdgcn_readlane(vcol, j);
                float r0 = rl_f(w0, j), r1 = rl_f(w1, j);
                float r2 = rl_f(w2, j), r3 = rl_f(w3, j);
                float wA = hf ? r1 : r0;
                float wB = hf ? r3 : r2;
                float2 xv = __half22float2(xph[(size_t)scol * 64 + lane]);
                acc0 = fmaf(wA, xv.x, acc0);
                acc1 = fmaf(wB, xv.y, acc1);
            };
            int j = 0;
            for (; j + 4 <= cnt; j += 4) { body(j); body(j + 1); body(j + 2); body(j + 3); }
            for (; j < cnt; ++j) body(j);
        }
        for (int s = 32; s >= 1; s >>= 1) {
            t0 += __shfl_xor(t0, s); t1 += __shfl_xor(t1, s);
            t2 += __shfl_xor(t2, s); t3 += __shfl_xor(t3, s);
        }
        float rd0 = 1.f / (t0 + sw0 + 1e-16f), rd1 = 1.f / (t1 + sw1 + 1e-16f);
        float rd2 = 1.f / (t2 + sw2 + 1e-16f), rd3 = 1.f / (t3 + sw3 + 1e-16f);
        float v0 = acc0 * (hf ? rd1 : rd0) + bias[lane];
        float v1 = acc1 * (hf ? rd3 : rd2) + bias[lane + 64];
        if (DO_ELU) {
            v0 = v0 > 0.f ? v0 : expm1f(v0);
            v1 = v1 > 0.f ? v1 : expm1f(v1);
        }
        out[(size_t)wid * D + lane] = v0;
        out[(size_t)wid * D + lane + 64] = v1;
    } else {
        float sd = s_dst[wid];
        float es = LRELU(s_src[wid] + sd);
        float m = es;
        for (int i = lane; i < deg; i += 64) {
            int c = col[off + i];
            m = fmaxf(m, LRELU(s_src[c] + sd));
        }
        for (int s = 32; s >= 1; s >>= 1) m = fmaxf(m, __shfl_xor(m, s));
        float sw = __expf(es - m);
        float2 xs = reinterpret_cast<const float2*>(xp2 + (size_t)wid * D)[lane];
        float acc0 = sw * xs.x, acc1 = sw * xs.y;
        float tsum = 0.f;
        for (int c0 = 0; c0 < deg; c0 += 64) {
            int rem = deg - c0;
            int cnt = rem < 64 ? rem : 64;
            int vcol = 0;
            float w = 0.f;
            if (lane < cnt) {
                vcol = col[off + c0 + lane];
                w = __expf(LRELU(s_src[vcol] + sd) - m);
                tsum += w;
            }
            auto body = [&](int j) {
                int scol = __builtin_amdgcn_readlane(vcol, j);
                float ww = rl_f(w, j);
                float2 xv = __half22float2(xph[(size_t)scol * 64 + lane]);
                acc0 = fmaf(ww, xv.x, acc0);
                acc1 = fmaf(ww, xv.y, acc1);
            };
            int j = 0;
            for (; j + 4 <= cnt; j += 4) { body(j); body(j + 1); body(j + 2); body(j + 3); }
            for (; j < cnt; ++j) body(j);
        }
        for (int s = 32; s >= 1; s >>= 1) tsum += __shfl_xor(tsum, s);
        float rd = 1.f / (tsum + sw + 1e-16f);
        float v0 = acc0 * rd + bias[lane];
        float v1 = acc1 * rd + bias[lane + 64];
        if (DO_ELU) {
            v0 = v0 > 0.f ? v0 : expm1f(v0);
            v1 = v1 > 0.f ? v1 : expm1f(v1);
        }
        out[(size_t)wid * D + lane] = v0;
        out[(size_t)wid * D + lane + 64] = v1;
    }
}

// ---------------- launch ----------------
extern "C" void kernel_launch(void* const* d_in, const int* in_sizes, int n_in,
                              void* d_out, int out_size, void* d_ws, size_t ws_size,
                              hipStream_t stream) {
    (void)n_in; (void)out_size; (void)ws_size;
    const float* x   = (const float*)d_in[0];
    const void*  ei  = d_in[1];
    const float* W1  = (const float*)d_in[2];
    const float* a1s = (const float*)d_in[3];
    const float* a1d = (const float*)d_in[4];
    const float* b1  = (const float*)d_in[5];
    const float* W2  = (const float*)d_in[6];
    const float* a2s = (const float*)d_in[7];
    const float* a2d = (const float*)d_in[8];
    const float* b2  = (const float*)d_in[9];
    const int N = in_sizes[0] / D;  // 100000
    const int E = in_sizes[1] / 2;  // 1600000
    float* out = (float*)d_out;

    char* p = (char*)d_ws;
    auto alloc = [&](size_t bytes) {
        char* q = p;
        p += (bytes + 255) & ~(size_t)255;
        return q;
    };
    float*   xp      = (float*)alloc((size_t)N * D * 4);     // paired f32
    __half2* xph     = (__half2*)alloc((size_t)N * 64 * 4);  // paired fp16
    float*   ssrc    = (float*)alloc((size_t)N * 4 * 4);
    float*   sdst    = (float*)alloc((size_t)N * 4 * 4);
    int*     count   = (int*)alloc((size_t)N * 4);
    int*     offsets = (int*)alloc((size_t)N * 4);
    int*     bsum    = (int*)alloc(256 * 4);
    int*     bsumex  = (int*)alloc(256 * 4);
    int*     flag    = (int*)alloc(256);
    int*     col     = (int*)alloc((size_t)E * 4);
    int*     rank    = (int*)alloc((size_t)E * 4);

    hipMemsetAsync(count, 0, (size_t)N * 4, stream);

    detect_i64<<<1, 64, 0, stream>>>((const unsigned int*)ei, flag);
    int eg = (E + 255) / 256;
    hist_kernel<<<eg, 256, 0, stream>>>(ei, flag, count, rank, E);
    int B = (N + 1023) / 1024;
    reduce_1024<<<B, 256, 0, stream>>>(count, bsum, N);
    scan_partials<<<1, 256, 0, stream>>>(bsumex, bsum, B);
    scan_final<<<B, 256, 0, stream>>>(count, bsumex, offsets, N);
    scatter_kernel<<<eg, 256, 0, stream>>>(ei, flag, offsets, rank, col, E);

    int gemmG = (N + 63) / 64;
    int nodeG = (N + 3) / 4;

    // ----- layer 1 (H=4, ELU) -----
    gemm_nn_128<<<gemmG, 256, 0, stream>>>(x, W1, xp, xph, N);
    score_kernel<4><<<nodeG, 256, 0, stream>>>(xp, a1s, a1d, ssrc, sdst, N);
    fused_node<4, true><<<nodeG, 256, 0, stream>>>(col, offsets, count, xp, xph, ssrc, sdst, b1, out, N);

    // ----- layer 2 (H=1, no activation) -----
    gemm_nn_128<<<gemmG, 256, 0, stream>>>(out, W2, xp, xph, N);
    score_kernel<1><<<nodeG, 256, 0, stream>>>(xp, a2s, a2d, ssrc, sdst, N);
    fused_node<1, false><<<nodeG, 256, 0, stream>>>(col, offsets, count, xp, xph, ssrc, sdst, b2, out, N);
}